// Round 4
// baseline (259.536 us; speedup 1.0000x reference)
//
#include <hip/hip_runtime.h>
#include <math.h>

#define Bq 8
#define Sq 2048
#define Hq 1024
#define QT 16          // attn rows per block (4 waves x 4 rows)
#define INV_SQRT_H (1.0f / 32.0f)

typedef float f32x4 __attribute__((ext_vector_type(4)));

__device__ __forceinline__ float waveReduceSum(float v) {
#pragma unroll
    for (int off = 32; off > 0; off >>= 1) v += __shfl_xor(v, off, 64);
    return v;
}

// ---------------------------------------------------------------------------
// prep: blocks 0..31 -> wq_eff[h] = sum_o Wq[o,h]*Wk[o]  (atomic o-chunks)
//       block  32    -> cb = (bq . Wk)/sqrt(H)
//       blocks 33..40-> per-batch min/max of sqi
// ---------------------------------------------------------------------------
__global__ void k_prep(const float* __restrict__ Wq, const float* __restrict__ Wk,
                       const float* __restrict__ bq, const float* __restrict__ sqi,
                       float* __restrict__ wq_eff, float* __restrict__ cb,
                       float* __restrict__ ext) {
    int bid = blockIdx.x, t = threadIdx.x;
    int wid = t >> 6, lane = t & 63;
    if (bid < 32) {
        int hc = bid & 3, oc = bid >> 2;
        int h = hc * 256 + t, o0 = oc * 128;
        float acc = 0.f;
#pragma unroll 4
        for (int o = 0; o < 128; ++o)
            acc += Wq[(size_t)(o0 + o) * Hq + h] * Wk[o0 + o];
        atomicAdd(&wq_eff[h], acc);
    } else if (bid == 32) {
        float acc = 0.f;
#pragma unroll
        for (int j = 0; j < 4; ++j) acc += bq[t * 4 + j] * Wk[t * 4 + j];
        acc = waveReduceSum(acc);
        __shared__ float red[4];
        if (lane == 0) red[wid] = acc;
        __syncthreads();
        if (t == 0) *cb = (red[0] + red[1] + red[2] + red[3]) * INV_SQRT_H;
    } else {
        int b = bid - 33;
        float mn = 1e30f, mx = -1e30f;
        for (int j = t; j < Sq; j += 256) {
            float v = sqi[b * Sq + j];
            mn = fminf(mn, v);
            mx = fmaxf(mx, v);
        }
#pragma unroll
        for (int off = 32; off > 0; off >>= 1) {
            mn = fminf(mn, __shfl_xor(mn, off, 64));
            mx = fmaxf(mx, __shfl_xor(mx, off, 64));
        }
        __shared__ float smn[4], smx[4];
        if (lane == 0) { smn[wid] = mn; smx[wid] = mx; }
        __syncthreads();
        if (t == 0) {
            ext[b]      = fminf(fminf(smn[0], smn[1]), fminf(smn[2], smn[3]));
            ext[Bq + b] = fmaxf(fmaxf(smx[0], smx[1]), fmaxf(smx[2], smx[3]));
        }
    }
}

// apos[q] = (pos[q,:] . wq_eff) / sqrt(H)   -- wave per 4 rows, 16 rows/block
__global__ void k_apos(const float* __restrict__ pos, const float* __restrict__ wq_eff,
                       float* __restrict__ apos) {
    int t = threadIdx.x, wid = t >> 6, lane = t & 63;
    int q0 = blockIdx.x * 16 + wid * 4;
    const float4* wp = (const float4*)wq_eff;
    float4 w0 = wp[lane], w1 = wp[lane + 64], w2 = wp[lane + 128], w3 = wp[lane + 192];
#pragma unroll
    for (int r = 0; r < 4; ++r) {
        const float4* pp = (const float4*)(pos + (size_t)(q0 + r) * Hq);
        float4 p0 = pp[lane], p1 = pp[lane + 64], p2 = pp[lane + 128], p3 = pp[lane + 192];
        float d = p0.x * w0.x + p0.y * w0.y + p0.z * w0.z + p0.w * w0.w
                + p1.x * w1.x + p1.y * w1.y + p1.z * w1.z + p1.w * w1.w
                + p2.x * w2.x + p2.y * w2.y + p2.z * w2.z + p2.w * w2.w
                + p3.x * w3.x + p3.y * w3.y + p3.z * w3.z + p3.w * w3.w;
        d = waveReduceSum(d);
        if (lane == 0) apos[q0 + r] = d * INV_SQRT_H;
    }
}

// attn[b,q,:] = softmax( a[b,q] * sqi[b,:] ), a computed in-kernel.
// wave owns 4 rows end-to-end (no block syncs in main loop); fused col-sums.
__global__ void __launch_bounds__(256) k_attn(
        const float* __restrict__ hidden, const float* __restrict__ apos,
        const float* __restrict__ wq_eff, const float* __restrict__ cbp,
        const float* __restrict__ sqi, const float* __restrict__ ext,
        float* __restrict__ attn, float* __restrict__ wcol) {
    int b = blockIdx.y, qt = blockIdx.x, t = threadIdx.x;
    int wid = t >> 6, lane = t & 63;
    __shared__ float sqi_s[Sq];
    __shared__ float colsum[Sq];
    {
        const float4* sp = (const float4*)(sqi + b * Sq);
        float4* ds = (float4*)sqi_s;
        ds[t]       = sp[t];
        ds[256 + t] = sp[256 + t];
    }
    float smin = ext[b], smax = ext[Bq + b];
    float cbv = *cbp;

    // ---- a-phase: wave computes a for its 4 rows (x . wq_eff)/32 + apos + cb
    const float4* wp = (const float4*)wq_eff;
    float4 w0 = wp[lane], w1 = wp[lane + 64], w2 = wp[lane + 128], w3 = wp[lane + 192];
    int q0 = qt * QT + wid * 4;
    float a[4];
#pragma unroll
    for (int r = 0; r < 4; ++r) {
        const float4* hp = (const float4*)(hidden + (size_t)(b * Sq + q0 + r) * Hq);
        float4 h0 = hp[lane], h1 = hp[lane + 64], h2 = hp[lane + 128], h3 = hp[lane + 192];
        float d = h0.x * w0.x + h0.y * w0.y + h0.z * w0.z + h0.w * w0.w
                + h1.x * w1.x + h1.y * w1.y + h1.z * w1.z + h1.w * w1.w
                + h2.x * w2.x + h2.y * w2.y + h2.z * w2.z + h2.w * w2.w
                + h3.x * w3.x + h3.y * w3.y + h3.z * w3.z + h3.w * w3.w;
        d = waveReduceSum(d);
        a[r] = d * INV_SQRT_H + apos[q0 + r] + cbv;
    }
    __syncthreads();   // sqi_s ready

    // ---- softmax phase: per row, lane covers 8 float4 chunks (32 cols)
    const float4* ss = (const float4*)sqi_s;
    float4 ca[8];
#pragma unroll
    for (int c = 0; c < 8; ++c) ca[c] = make_float4(0.f, 0.f, 0.f, 0.f);

#pragma unroll
    for (int r = 0; r < 4; ++r) {
        float aa = a[r];
        float m = (aa > 0.f) ? aa * smax : aa * smin;   // exact row max
        float4 e[8];
        float s = 0.f;
#pragma unroll
        for (int c = 0; c < 8; ++c) {
            float4 sv = ss[lane + 64 * c];
            e[c].x = __expf(aa * sv.x - m);
            e[c].y = __expf(aa * sv.y - m);
            e[c].z = __expf(aa * sv.z - m);
            e[c].w = __expf(aa * sv.w - m);
            s += e[c].x + e[c].y + e[c].z + e[c].w;
        }
        s = waveReduceSum(s);
        float rinv = 1.0f / s;
        f32x4* orow = (f32x4*)(attn + (size_t)(b * Sq + q0 + r) * Sq);
#pragma unroll
        for (int c = 0; c < 8; ++c) {
            f32x4 p;
            p.x = e[c].x * rinv; p.y = e[c].y * rinv;
            p.z = e[c].z * rinv; p.w = e[c].w * rinv;
            __builtin_nontemporal_store(p, &orow[lane + 64 * c]);
            ca[c].x += p.x; ca[c].y += p.y; ca[c].z += p.z; ca[c].w += p.w;
        }
    }

    // ---- combine per-wave column sums in LDS (serialized waves), then atomics
    float4* cs = (float4*)colsum;
    if (wid == 0) {
#pragma unroll
        for (int c = 0; c < 8; ++c) cs[lane + 64 * c] = ca[c];
    }
    __syncthreads();
#pragma unroll
    for (int w = 1; w < 4; ++w) {
        if (wid == w) {
#pragma unroll
            for (int c = 0; c < 8; ++c) {
                float4 v = cs[lane + 64 * c];
                v.x += ca[c].x; v.y += ca[c].y; v.z += ca[c].z; v.w += ca[c].w;
                cs[lane + 64 * c] = v;
            }
        }
        __syncthreads();
    }
#pragma unroll
    for (int j = 0; j < 8; ++j)
        atomicAdd(&wcol[b * Sq + j * 256 + t], colsum[j * 256 + t]);
}

// y[b,h] = sum_kk (wcol[b,kk]/S) * (hidden[b,kk,h] + pos[kk,h])
__global__ void k_y(const float* __restrict__ hidden, const float* __restrict__ pos,
                    const float* __restrict__ wcol, float* __restrict__ y) {
    int b = blockIdx.y, kc = blockIdx.x, t = threadIdx.x;
    int kk0 = kc * (Sq / 32);      // 64 rows per block
    float4 acc = {0, 0, 0, 0};
    for (int i = 0; i < Sq / 32; ++i) {
        int kk = kk0 + i;
        float wv = wcol[b * Sq + kk] * (1.0f / Sq);
        float4 hv = ((const float4*)(hidden + ((size_t)(b * Sq + kk)) * Hq))[t];
        float4 pv = ((const float4*)(pos + (size_t)kk * Hq))[t];
        acc.x += wv * (hv.x + pv.x);
        acc.y += wv * (hv.y + pv.y);
        acc.z += wv * (hv.z + pv.z);
        acc.w += wv * (hv.w + pv.w);
    }
    atomicAdd(&y[b * Hq + t * 4 + 0], acc.x);
    atomicAdd(&y[b * Hq + t * 4 + 1], acc.y);
    atomicAdd(&y[b * Hq + t * 4 + 2], acc.z);
    atomicAdd(&y[b * Hq + t * 4 + 3], acc.w);
}

// ctx[b,h] = sum_h' Wv[h,h'] * y[b,h'] + bv[h]   (h' split in 4 chunks)
__global__ void k_ctx(const float* __restrict__ Wv, const float* __restrict__ bv,
                      const float* __restrict__ y, float* __restrict__ ctx) {
    int b = blockIdx.y, kc = blockIdx.z, t = threadIdx.x;
    int h = blockIdx.x * 256 + t;
    __shared__ float ys[256];
    ys[t] = y[b * Hq + kc * 256 + t];
    __syncthreads();
    const float4* wrow = (const float4*)(Wv + (size_t)h * Hq + kc * 256);
    float acc = 0.f;
#pragma unroll 8
    for (int j = 0; j < 64; ++j) {
        float4 w4 = wrow[j];
        acc += w4.x * ys[j * 4 + 0] + w4.y * ys[j * 4 + 1] +
               w4.z * ys[j * 4 + 2] + w4.w * ys[j * 4 + 3];
    }
    if (kc == 0) acc += bv[h];
    atomicAdd(&ctx[b * Hq + h], acc);
}

extern "C" void kernel_launch(void* const* d_in, const int* in_sizes, int n_in,
                              void* d_out, int out_size, void* d_ws, size_t ws_size,
                              hipStream_t stream) {
    const float* hidden = (const float*)d_in[0];
    const float* sqi    = (const float*)d_in[1];
    const float* pos    = (const float*)d_in[2];
    const float* Wq     = (const float*)d_in[3];
    const float* bq     = (const float*)d_in[4];
    const float* Wk     = (const float*)d_in[5];
    // bk (d_in[6]) shifts every score in a row equally -> cancels in softmax
    const float* Wv     = (const float*)d_in[7];
    const float* bv     = (const float*)d_in[8];

    float* out  = (float*)d_out;
    float* ctx  = out;                    // [B,H]
    float* attn = out + Bq * Hq;          // [B,S,S]

    // workspace layout (floats)
    float* ws     = (float*)d_ws;
    float* wq_eff = ws;                   // 1024
    float* wcol   = ws + 1024;            // 16384
    float* y      = ws + 17408;           // 8192   (zeroed region ends: 25600)
    float* ext    = ws + 25600;           // 16 (min[8], max[8])
    float* cb     = ws + 25616;           // 1
    float* apos   = ws + 25632;           // 2048

    (void)hipMemsetAsync(ws, 0, 25600 * sizeof(float), stream);    // wq_eff+wcol+y
    (void)hipMemsetAsync(ctx, 0, Bq * Hq * sizeof(float), stream); // ctx accumulators

    k_prep<<<41, 256, 0, stream>>>(Wq, Wk, bq, sqi, wq_eff, cb, ext);
    k_apos<<<Sq / 16, 256, 0, stream>>>(pos, wq_eff, apos);
    k_attn<<<dim3(Sq / QT, Bq), 256, 0, stream>>>(hidden, apos, wq_eff, cb,
                                                  sqi, ext, attn, wcol);
    k_y   <<<dim3(32, Bq), 256, 0, stream>>>(hidden, pos, wcol, y);
    k_ctx <<<dim3(Hq / 256, Bq, 4), 256, 0, stream>>>(Wv, bv, y, ctx);
}